// Round 9
// baseline (186.124 us; speedup 1.0000x reference)
//
#include <hip/hip_runtime.h>
#include <hip/hip_fp16.h>
#include <math.h>

#define THREADS 256
#define NPB 512           // nodes per bin
#define SHIFT 9
#define MASK 511
#define MAX_BINS 256
#define CAPE 20480        // per-bin capacity (true mean 16384, +8 sigma, +3*512 pad)
#define BIN_BLOCKS 512
#define SENT (-1)         // sentinel for pad slots (valid packed edges < 2^31)

typedef int ivec4 __attribute__((ext_vector_type(4)));  // nt-load-capable int4

// ===================== stage 1: bin edges by target>>9 =======================
// R17/R19 structure; NO nt here — pass B depends on pass A's L2-warm col/row.

__global__ void __launch_bounds__(512) k_bin(const int* __restrict__ row,
                                             const int* __restrict__ col,
                                             int e, int* __restrict__ binCnt,
                                             int* __restrict__ binned) {
    __shared__ int hist[MAX_BINS];
    __shared__ int cur[MAX_BINS];
    __shared__ int baseg[MAX_BINS];
    __shared__ int lofs[MAX_BINS];
    __shared__ int scn[MAX_BINS];
    extern __shared__ int sbuf2[];   // per ints
    int per = (((e + (int)gridDim.x - 1) / (int)gridDim.x) + 3) & ~3;
    int e0 = blockIdx.x * per;
    if (e0 >= e) return;
    int e1 = min(e0 + per, e);
    int cntL = e1 - e0;
    int tid = threadIdx.x;
    if (tid < MAX_BINS) { hist[tid] = 0; cur[tid] = 0; }
    __syncthreads();
    int nq = cntL >> 2;
    const int4* r4 = (const int4*)(row + e0);
    const int4* c4 = (const int4*)(col + e0);
    // pass A: histogram only (col read, 4 LDS atomics per int4)
    for (int q = tid; q < nq; q += 512) {
        int4 c = c4[q];
        atomicAdd(&hist[c.x >> SHIFT], 1);
        atomicAdd(&hist[c.y >> SHIFT], 1);
        atomicAdd(&hist[c.z >> SHIFT], 1);
        atomicAdd(&hist[c.w >> SHIFT], 1);
    }
    for (int li = (nq << 2) + tid; li < cntL; li += 512) {
        atomicAdd(&hist[col[e0 + li] >> SHIFT], 1);
    }
    __syncthreads();
    if (tid < MAX_BINS) {
        int h = hist[tid];
        baseg[tid] = (h > 0) ? atomicAdd(&binCnt[tid], (h + 3) & ~3) : 0;  // x4 pad
        scn[tid] = h;
    }
    __syncthreads();
    for (int off = 1; off < MAX_BINS; off <<= 1) {
        int a = (tid >= off && tid < MAX_BINS) ? scn[tid - off] : 0;
        __syncthreads();
        if (tid < MAX_BINS) scn[tid] += a;
        __syncthreads();
    }
    if (tid < MAX_BINS) lofs[tid] = scn[tid] - hist[tid];
    __syncthreads();
    // pass B: re-read row+col, pack, scatter bin-contiguous into sbuf2
    for (int q = tid; q < nq; q += 512) {
        int4 r = r4[q], c = c4[q];
        int b0 = c.x >> SHIFT, b1 = c.y >> SHIFT, b2 = c.z >> SHIFT, b3 = c.w >> SHIFT;
        int p0 = lofs[b0] + atomicAdd(&cur[b0], 1);
        sbuf2[p0] = (r.x << SHIFT) | (c.x & MASK);
        int p1 = lofs[b1] + atomicAdd(&cur[b1], 1);
        sbuf2[p1] = (r.y << SHIFT) | (c.y & MASK);
        int p2 = lofs[b2] + atomicAdd(&cur[b2], 1);
        sbuf2[p2] = (r.z << SHIFT) | (c.z & MASK);
        int p3 = lofs[b3] + atomicAdd(&cur[b3], 1);
        sbuf2[p3] = (r.w << SHIFT) | (c.w & MASK);
    }
    for (int li = (nq << 2) + tid; li < cntL; li += 512) {
        int c = col[e0 + li], r = row[e0 + li], b = c >> SHIFT;
        int p = lofs[b] + atomicAdd(&cur[b], 1);
        sbuf2[p] = (r << SHIFT) | (c & MASK);
    }
    __syncthreads();
    // pass C: wave-per-bin flush, int4 chunks (baseg multiple of 4)
    int wv = tid >> 6, ln = tid & 63;
    for (int b = wv; b < MAX_BINS; b += 8) {
        int len = hist[b];
        if (len == 0) continue;
        int lo = lofs[b];
        int gb = baseg[b];
        int n4 = (len + 3) >> 2;
        for (int i4 = ln; i4 < n4; i4 += 64) {
            int base = i4 * 4;
            int4 v;
            v.x = (base + 0 < len) ? sbuf2[lo + base + 0] : SENT;
            v.y = (base + 1 < len) ? sbuf2[lo + base + 1] : SENT;
            v.z = (base + 2 < len) ? sbuf2[lo + base + 2] : SENT;
            v.w = (base + 3 < len) ? sbuf2[lo + base + 3] : SENT;
            int pos = gb + base;
            if (pos + 4 <= CAPE) *(int4*)(binned + b * CAPE + pos) = v;
        }
    }
}

// ======= stage 2 (FUSED): per-bin counting sort -> CSR + deg + dinv ==========
// + layer-1 transform. R19 register-cached binned; unchanged.

__global__ void __launch_bounds__(1024) k_sort(const int* __restrict__ binned,
                                               const int* __restrict__ binCnt,
                                               int* __restrict__ csr,
                                               int* __restrict__ gptr,
                                               int* __restrict__ gcnt,
                                               float* __restrict__ dinv,
                                               const float* __restrict__ x,
                                               const float* __restrict__ W1,
                                               __half* __restrict__ z1h, int n) {
    __shared__ int cnt[NPB];
    __shared__ int scn[NPB];
    __shared__ float sW[25 * 16];
    int b = blockIdx.x;
    int t = threadIdx.x;
    if (t < NPB) cnt[t] = 0;
    if (t < 25 * 16) sW[t] = W1[t];
    __syncthreads();
    int m = min(binCnt[b], CAPE);   // multiple of 4 (padded reservations)
    int m4 = m >> 2;
    const int4* eb4 = (const int4*)(binned + b * CAPE);
    const int4 S4 = make_int4(SENT, SENT, SENT, SENT);
    int4 q0 = (t          < m4) ? eb4[t]          : S4;
    int4 q1 = (t + 1024   < m4) ? eb4[t + 1024]   : S4;
    int4 q2 = (t + 2048   < m4) ? eb4[t + 2048]   : S4;
    int4 q3 = (t + 3072   < m4) ? eb4[t + 3072]   : S4;
    int4 q4 = (t + 4096   < m4) ? eb4[t + 4096]   : S4;
#define H4(q) { \
    if (q.x != SENT) atomicAdd(&cnt[q.x & MASK], 1); \
    if (q.y != SENT) atomicAdd(&cnt[q.y & MASK], 1); \
    if (q.z != SENT) atomicAdd(&cnt[q.z & MASK], 1); \
    if (q.w != SENT) atomicAdd(&cnt[q.w & MASK], 1); }
    H4(q0) H4(q1) H4(q2) H4(q3) H4(q4)
#undef H4
    __syncthreads();
    int v = 0, pv = 0;
    if (t < NPB) {
        v = cnt[t];
        pv = (v + 3) & ~3;  // 4-aligned degree for csr segment alignment
        scn[t] = pv;
    }
    __syncthreads();
    for (int off = 1; off < NPB; off <<= 1) {
        int a = (t >= off && t < NPB) ? scn[t - off] : 0;
        __syncthreads();
        if (t < NPB) scn[t] += a;
        __syncthreads();
    }
    int node = b * NPB + t;
    float di = rsqrtf((float)(v + 1));
    if (t < NPB) {
        int excl = scn[t] - pv;  // multiple of 4
        if (node < n) {
            gptr[node] = b * CAPE + excl;
            gcnt[node] = v;
            dinv[node] = di;
        }
        cnt[t] = excl;  // reuse as cursor
    }
    __syncthreads();
#define P4(q) { \
    int e, slot; \
    e = q.x; if (e != SENT) { slot = atomicAdd(&cnt[e & MASK], 1); if (slot < CAPE) csr[b * CAPE + slot] = e >> SHIFT; } \
    e = q.y; if (e != SENT) { slot = atomicAdd(&cnt[e & MASK], 1); if (slot < CAPE) csr[b * CAPE + slot] = e >> SHIFT; } \
    e = q.z; if (e != SENT) { slot = atomicAdd(&cnt[e & MASK], 1); if (slot < CAPE) csr[b * CAPE + slot] = e >> SHIFT; } \
    e = q.w; if (e != SENT) { slot = atomicAdd(&cnt[e & MASK], 1); if (slot < CAPE) csr[b * CAPE + slot] = e >> SHIFT; } }
    P4(q0) P4(q1) P4(q2) P4(q3) P4(q4)
#undef P4
    // fused layer-1 transform for this bin's nodes
    if (t < NPB && node < n) {
        const float* xr = x + (size_t)node * 25;
        float xi[25];
#pragma unroll
        for (int k = 0; k < 25; k++) xi[k] = xr[k];
        union { int4 q[2]; __half h[16]; } u;
#pragma unroll
        for (int c = 0; c < 16; c++) {
            float a = 0.f;
#pragma unroll
            for (int k = 0; k < 25; k++) a = fmaf(xi[k], sW[k * 16 + c], a);
            u.h[c] = __float2half(a * di);
        }
        int4* o = (int4*)(z1h + (size_t)node * 16);
        o[0] = u.q[0];
        o[1] = u.q[1];
    }
}

// --- standalone xform1 (fallback path only) ----------------------------------
__global__ void __launch_bounds__(256) k_xform1(const float* __restrict__ x,
                                                const float* __restrict__ W1,
                                                const float* __restrict__ dinv,
                                                __half* __restrict__ z1h, int n) {
    __shared__ float sW[25 * 16];
    for (int t = threadIdx.x; t < 25 * 16; t += 256) sW[t] = W1[t];
    __syncthreads();
    long node = (long)blockIdx.x * 256 + threadIdx.x;
    if (node >= n) return;
    const float* xr = x + node * 25;
    float xi[25];
#pragma unroll
    for (int k = 0; k < 25; k++) xi[k] = xr[k];
    float di = dinv[node];
    union { int4 q[2]; __half h[16]; } u;
#pragma unroll
    for (int c = 0; c < 16; c++) {
        float a = 0.f;
#pragma unroll
        for (int k = 0; k < 25; k++) a = fmaf(xi[k], sW[k * 16 + c], a);
        u.h[c] = __float2half(a * di);
    }
    int4* o = (int4*)(z1h + node * 16);
    o[0] = u.q[0];
    o[1] = u.q[1];
}

// --- gather layer 1 + bias/relu + @W2: 8 lanes/node, half2 loads -------------
// R26: 8 edges/iter MLP unroll (-4us, confirmed concurrency-sensitive).
// R27: csr loads NON-TEMPORAL (single-use stream) so the 12.8MB csr stream
// stops evicting the 3.2MB z1h table from the 4MB per-XCD L2. z1h loads stay
// temporal (heavy reuse: each node read by ~32 neighbors).
__global__ void k_gather1(const int* __restrict__ ptr, const int* __restrict__ cnt,
                          const int* __restrict__ csr, const __half* __restrict__ z1h,
                          const float* __restrict__ dinv,
                          const float* __restrict__ b1, const float* __restrict__ W2,
                          __half2* __restrict__ z2h, int n) {
    int g = threadIdx.x >> 3;
    int c2 = threadIdx.x & 7;
    int node = blockIdx.x * 32 + g;
    if (node >= n) return;
    const __half2* z1p = (const __half2*)z1h;
    int beg = ptr[node], d = cnt[node];
    __half2 sv = z1p[(size_t)node * 8 + c2];
    float a0 = __low2float(sv), a1 = __high2float(sv);
    int e = 0;
    for (; e + 8 <= d; e += 8) {
        ivec4 s0 = __builtin_nontemporal_load((const ivec4*)(csr + beg + e));      // 16B nt
        ivec4 s1 = __builtin_nontemporal_load((const ivec4*)(csr + beg + e + 4));  // 16B nt
        __half2 v0 = z1p[(size_t)s0[0] * 8 + c2];
        __half2 v1 = z1p[(size_t)s0[1] * 8 + c2];
        __half2 v2 = z1p[(size_t)s0[2] * 8 + c2];
        __half2 v3 = z1p[(size_t)s0[3] * 8 + c2];
        __half2 v4 = z1p[(size_t)s1[0] * 8 + c2];
        __half2 v5 = z1p[(size_t)s1[1] * 8 + c2];
        __half2 v6 = z1p[(size_t)s1[2] * 8 + c2];
        __half2 v7 = z1p[(size_t)s1[3] * 8 + c2];
        a0 += ((__low2float(v0) + __low2float(v1)) + (__low2float(v2) + __low2float(v3))) +
              ((__low2float(v4) + __low2float(v5)) + (__low2float(v6) + __low2float(v7)));
        a1 += ((__high2float(v0) + __high2float(v1)) + (__high2float(v2) + __high2float(v3))) +
              ((__high2float(v4) + __high2float(v5)) + (__high2float(v6) + __high2float(v7)));
    }
    for (; e + 4 <= d; e += 4) {
        ivec4 s = __builtin_nontemporal_load((const ivec4*)(csr + beg + e));
        __half2 v0 = z1p[(size_t)s[0] * 8 + c2];
        __half2 v1 = z1p[(size_t)s[1] * 8 + c2];
        __half2 v2 = z1p[(size_t)s[2] * 8 + c2];
        __half2 v3 = z1p[(size_t)s[3] * 8 + c2];
        a0 += (__low2float(v0) + __low2float(v1)) + (__low2float(v2) + __low2float(v3));
        a1 += (__high2float(v0) + __high2float(v1)) + (__high2float(v2) + __high2float(v3));
    }
    for (; e < d; e++) {
        __half2 v = z1p[(size_t)__builtin_nontemporal_load(csr + beg + e) * 8 + c2];
        a0 += __low2float(v);
        a1 += __high2float(v);
    }
    float di = dinv[node];
    int cA = c2 * 2, cB = c2 * 2 + 1;
    float hA = fmaxf(fmaf(di, a0, b1[cA]), 0.f);
    float hB = fmaxf(fmaf(di, a1, b1[cB]), 0.f);
    float p0 = hA * W2[cA * 2 + 0] + hB * W2[cB * 2 + 0];
    float p1 = hA * W2[cA * 2 + 1] + hB * W2[cB * 2 + 1];
#pragma unroll
    for (int m = 1; m < 8; m <<= 1) {
        p0 += __shfl_xor(p0, m, 8);
        p1 += __shfl_xor(p1, m, 8);
    }
    if (c2 == 0) z2h[node] = __floats2half2_rn(di * p0, di * p1);
}

// --- gather layer 2: 8 lanes/node + bias + log_softmax(2) --------------------
// R27: csr nt loads + 4 edges/lane/iter (z2h 0.4MB stays L2-resident).
__global__ void k_gather2(const int* __restrict__ ptr, const int* __restrict__ cnt,
                          const int* __restrict__ csr, const __half2* __restrict__ z2h,
                          const float* __restrict__ dinv,
                          const float* __restrict__ b2, float* __restrict__ out, int n) {
    int g = threadIdx.x >> 3;
    int c = threadIdx.x & 7;
    int node = blockIdx.x * 32 + g;
    if (node >= n) return;
    int beg = ptr[node], d = cnt[node];
    float a0 = 0.f, a1 = 0.f;
    int e = c;
    for (; e + 24 < d; e += 32) {
        int i0 = __builtin_nontemporal_load(csr + beg + e);
        int i1 = __builtin_nontemporal_load(csr + beg + e + 8);
        int i2 = __builtin_nontemporal_load(csr + beg + e + 16);
        int i3 = __builtin_nontemporal_load(csr + beg + e + 24);
        __half2 w0 = z2h[i0];
        __half2 w1 = z2h[i1];
        __half2 w2 = z2h[i2];
        __half2 w3 = z2h[i3];
        a0 += (__low2float(w0) + __low2float(w1)) + (__low2float(w2) + __low2float(w3));
        a1 += (__high2float(w0) + __high2float(w1)) + (__high2float(w2) + __high2float(w3));
    }
    for (; e < d; e += 8) {
        __half2 v = z2h[__builtin_nontemporal_load(csr + beg + e)];
        a0 += __low2float(v);
        a1 += __high2float(v);
    }
#pragma unroll
    for (int m = 1; m < 8; m <<= 1) {
        a0 += __shfl_xor(a0, m, 8);
        a1 += __shfl_xor(a1, m, 8);
    }
    if (c == 0) {
        __half2 self = z2h[node];
        a0 += __low2float(self);
        a1 += __high2float(self);
        float di = dinv[node];
        float h0 = fmaf(di, a0, b2[0]);
        float h1 = fmaf(di, a1, b2[1]);
        float mx = fmaxf(h0, h1);
        float lse = mx + log1pf(expf(fminf(h0, h1) - mx));
        ((float2*)out)[node] = make_float2(h0 - lse, h1 - lse);
    }
}

// ===================== fallback: round-2 CSR pipeline ========================

__global__ void k_zero(int* cnt, int n) {
    int i = blockIdx.x * blockDim.x + threadIdx.x;
    if (i < n) cnt[i] = 0;
}

__global__ void k_count_pos(const int* __restrict__ col, int e,
                            int* __restrict__ cnt, int* __restrict__ pos) {
    int i = blockIdx.x * blockDim.x + threadIdx.x;
    if (i < e) pos[i] = atomicAdd(&cnt[col[i]], 1);
}

__global__ void k_scan1(const int* __restrict__ cnt, int n,
                        int* __restrict__ excl, int* __restrict__ bsum) {
    __shared__ int s[256];
    int i = blockIdx.x * 256 + threadIdx.x;
    int v = (i < n) ? cnt[i] : 0;
    s[threadIdx.x] = v;
    __syncthreads();
    for (int off = 1; off < 256; off <<= 1) {
        int t = (threadIdx.x >= off) ? s[threadIdx.x - off] : 0;
        __syncthreads();
        s[threadIdx.x] += t;
        __syncthreads();
    }
    if (i < n) excl[i] = s[threadIdx.x] - v;
    if (threadIdx.x == 255) bsum[blockIdx.x] = s[255];
}

__global__ void k_scan2(int* __restrict__ bsum, int nb) {
    __shared__ int s[1024];
    int v = (threadIdx.x < nb) ? bsum[threadIdx.x] : 0;
    s[threadIdx.x] = v;
    __syncthreads();
    for (int off = 1; off < 1024; off <<= 1) {
        int t = (threadIdx.x >= off) ? s[threadIdx.x - off] : 0;
        __syncthreads();
        s[threadIdx.x] += t;
        __syncthreads();
    }
    if (threadIdx.x < nb) bsum[threadIdx.x] = s[threadIdx.x] - v;
}

__global__ void k_scan3(int* __restrict__ excl, const int* __restrict__ boff, int n) {
    int i = blockIdx.x * 256 + threadIdx.x;
    if (i < n) excl[i] += boff[blockIdx.x];
}

__global__ void k_place(const int* __restrict__ row, const int* __restrict__ col,
                        const int* __restrict__ pos, const int* __restrict__ ptr,
                        int e, int* __restrict__ csr) {
    int i = blockIdx.x * blockDim.x + threadIdx.x;
    if (i >= e) return;
    csr[ptr[col[i]] + pos[i]] = row[i];
}

__global__ void k_dinv_from_cnt(const int* __restrict__ cnt, float* __restrict__ dinv, int n) {
    int i = blockIdx.x * blockDim.x + threadIdx.x;
    if (i < n) dinv[i] = rsqrtf((float)(cnt[i] + 1));
}

__global__ void k_gather1_fb(const int* __restrict__ ptr, const int* __restrict__ cnt,
                             const int* __restrict__ csr, const __half* __restrict__ z1h,
                             const float* __restrict__ dinv,
                             const float* __restrict__ b1, const float* __restrict__ W2,
                             __half2* __restrict__ z2h, int n) {
    int g = threadIdx.x >> 3;
    int c2 = threadIdx.x & 7;
    int node = blockIdx.x * 32 + g;
    if (node >= n) return;
    const __half2* z1p = (const __half2*)z1h;
    int beg = ptr[node], d = cnt[node];
    __half2 sv = z1p[(size_t)node * 8 + c2];
    float a0 = __low2float(sv), a1 = __high2float(sv);
    for (int e = 0; e < d; e++) {
        __half2 v = z1p[(size_t)csr[beg + e] * 8 + c2];
        a0 += __low2float(v);
        a1 += __high2float(v);
    }
    float di = dinv[node];
    int cA = c2 * 2, cB = c2 * 2 + 1;
    float hA = fmaxf(fmaf(di, a0, b1[cA]), 0.f);
    float hB = fmaxf(fmaf(di, a1, b1[cB]), 0.f);
    float p0 = hA * W2[cA * 2 + 0] + hB * W2[cB * 2 + 0];
    float p1 = hA * W2[cA * 2 + 1] + hB * W2[cB * 2 + 1];
#pragma unroll
    for (int m = 1; m < 8; m <<= 1) {
        p0 += __shfl_xor(p0, m, 8);
        p1 += __shfl_xor(p1, m, 8);
    }
    if (c2 == 0) z2h[node] = __floats2half2_rn(di * p0, di * p1);
}

// ============================== host launcher ================================

extern "C" void kernel_launch(void* const* d_in, const int* in_sizes, int n_in,
                              void* d_out, int out_size, void* d_ws, size_t ws_size,
                              hipStream_t stream) {
    const float* x  = (const float*)d_in[0];
    const int*   ei = (const int*)d_in[1];
    const float* W1 = (const float*)d_in[2];
    const float* b1 = (const float*)d_in[3];
    const float* W2 = (const float*)d_in[4];
    const float* b2 = (const float*)d_in[5];
    float* out = (float*)d_out;

    const int N = in_sizes[0] / 25;
    const int E = in_sizes[1] / 2;
    const int* row = ei;
    const int* col = ei + E;

    const int nbins = (N + NPB - 1) / NPB;
    const int gN = (N + THREADS - 1) / THREADS;
    const int gE = (E + THREADS - 1) / THREADS;

    size_t off = 0;
    auto take = [&](size_t bytes) { size_t o = off; off = (off + bytes + 255) & ~(size_t)255; return o; };
    size_t o_binCnt = take(MAX_BINS * sizeof(int));
    size_t o_binned = take((size_t)nbins * CAPE * sizeof(int));
    size_t o_csr    = take((size_t)nbins * CAPE * sizeof(int));
    size_t o_ptr    = take((size_t)N * sizeof(int));
    size_t o_cnt    = take((size_t)N * sizeof(int));
    size_t o_dinv   = take((size_t)N * sizeof(float));
    size_t o_z1h    = take((size_t)N * 16 * sizeof(__half));
    size_t o_z2h    = take((size_t)N * sizeof(__half2));
    size_t need_v17 = off;

    // bin load: mu + 8*sigma + 3*NPB pad (covers both x4 reservation pad and
    // csr alignment pad, each bounded by 3*BIN_BLOCKS=1536=3*NPB)
    double mu = (double)E / (double)nbins;
    bool cap_ok = (mu + 8.0 * sqrt(mu) + 3.0 * NPB) < (double)CAPE;
    const int per = (((E + BIN_BLOCKS - 1) / BIN_BLOCKS) + 3) & ~3;
    size_t dynLds = (size_t)per * 4 + 64;  // sbuf2 only (4B/edge)
    bool lds_ok = dynLds <= 60 * 1024;
    bool use_v17 = (nbins <= MAX_BINS) && (ws_size >= need_v17) &&
                   (N <= NPB * MAX_BINS) && cap_ok && lds_ok &&
                   (3 * BIN_BLOCKS <= 3 * NPB);

    char* wsb = (char*)d_ws;
    if (use_v17) {
        int*     binCnt = (int*)(wsb + o_binCnt);
        int*     binned = (int*)(wsb + o_binned);
        int*     csr    = (int*)(wsb + o_csr);
        int*     ptr    = (int*)(wsb + o_ptr);
        int*     cnt    = (int*)(wsb + o_cnt);
        float*   dinv   = (float*)(wsb + o_dinv);
        __half*  z1h    = (__half*)(wsb + o_z1h);
        __half2* z2h    = (__half2*)(wsb + o_z2h);

        hipMemsetAsync(binCnt, 0, MAX_BINS * sizeof(int), stream);
        k_bin<<<BIN_BLOCKS, 512, dynLds, stream>>>(row, col, E, binCnt, binned);
        k_sort<<<nbins, 1024, 0, stream>>>(binned, binCnt, csr, ptr, cnt, dinv, x, W1, z1h, N);
        k_gather1<<<(N + 31) / 32, 256, 0, stream>>>(ptr, cnt, csr, z1h, dinv, b1, W2, z2h, N);
        k_gather2<<<(N + 31) / 32, 256, 0, stream>>>(ptr, cnt, csr, z2h, dinv, b2, out, N);
    } else {
        char* w = wsb;
        int*     cnt  = (int*)w;     w += (size_t)N * sizeof(int);
        int*     ptr  = (int*)w;     w += (size_t)N * sizeof(int);
        int*     pos  = (int*)w;     w += (size_t)E * sizeof(int);
        int*     csr  = (int*)w;     w += (size_t)E * sizeof(int);
        int*     bsum = (int*)w;     w += (size_t)1024 * sizeof(int);
        float*   dinv = (float*)w;   w += (size_t)N * sizeof(float);
        __half*  z1h  = (__half*)w;  w += (size_t)N * 16 * sizeof(__half);
        __half2* z2h  = (__half2*)w; w += (size_t)N * sizeof(__half2);
        const int NB = (N + 255) / 256;

        k_zero<<<gN, THREADS, 0, stream>>>(cnt, N);
        k_count_pos<<<gE, THREADS, 0, stream>>>(col, E, cnt, pos);
        k_scan1<<<NB, 256, 0, stream>>>(cnt, N, ptr, bsum);
        k_scan2<<<1, 1024, 0, stream>>>(bsum, NB);
        k_scan3<<<NB, 256, 0, stream>>>(ptr, bsum, N);
        k_place<<<gE, THREADS, 0, stream>>>(row, col, pos, ptr, E, csr);
        k_dinv_from_cnt<<<gN, THREADS, 0, stream>>>(cnt, dinv, N);
        k_xform1<<<gN, 256, 0, stream>>>(x, W1, dinv, z1h, N);
        k_gather1_fb<<<(N + 31) / 32, 256, 0, stream>>>(ptr, cnt, csr, z1h, dinv, b1, W2, z2h, N);
        k_gather2<<<(N + 31) / 32, 256, 0, stream>>>(ptr, cnt, csr, z2h, dinv, b2, out, N);
    }
}

// Round 10
// 171.889 us; speedup vs baseline: 1.0828x; 1.0828x over previous
//
#include <hip/hip_runtime.h>
#include <hip/hip_fp16.h>
#include <math.h>

#define THREADS 256
#define NPB 512           // nodes per bin
#define SHIFT 9
#define MASK 511
#define MAX_BINS 256
#define CAPE 20480        // per-bin capacity (true mean 16384, +8 sigma, +3*512 pad)
#define BIN_BLOCKS 512
#define SENT (-1)         // sentinel for pad slots (valid packed edges < 2^31)

// ===================== stage 1: bin edges by target>>9 =======================
// R17: reservations padded to x4; pass C flushes int4 chunks, SENT pads.
// R19: no sbuf/sbin staging; pass A histograms col; pass B re-reads row/col.
// R28: byte-exact revert to R26 (175.5us session best). R27's nt csr loads
// regressed +10.6us: nt skips L2 ALLOCATION, killing the 64B-line reuse the
// csr stream itself depends on (4 int4/line). "Single-use" = lines, not loads.

__global__ void __launch_bounds__(512) k_bin(const int* __restrict__ row,
                                             const int* __restrict__ col,
                                             int e, int* __restrict__ binCnt,
                                             int* __restrict__ binned) {
    __shared__ int hist[MAX_BINS];
    __shared__ int cur[MAX_BINS];
    __shared__ int baseg[MAX_BINS];
    __shared__ int lofs[MAX_BINS];
    __shared__ int scn[MAX_BINS];
    extern __shared__ int sbuf2[];   // per ints
    int per = (((e + (int)gridDim.x - 1) / (int)gridDim.x) + 3) & ~3;
    int e0 = blockIdx.x * per;
    if (e0 >= e) return;
    int e1 = min(e0 + per, e);
    int cntL = e1 - e0;
    int tid = threadIdx.x;
    if (tid < MAX_BINS) { hist[tid] = 0; cur[tid] = 0; }
    __syncthreads();
    int nq = cntL >> 2;
    const int4* r4 = (const int4*)(row + e0);
    const int4* c4 = (const int4*)(col + e0);
    // pass A: histogram only (col read, 4 LDS atomics per int4)
    for (int q = tid; q < nq; q += 512) {
        int4 c = c4[q];
        atomicAdd(&hist[c.x >> SHIFT], 1);
        atomicAdd(&hist[c.y >> SHIFT], 1);
        atomicAdd(&hist[c.z >> SHIFT], 1);
        atomicAdd(&hist[c.w >> SHIFT], 1);
    }
    for (int li = (nq << 2) + tid; li < cntL; li += 512) {
        atomicAdd(&hist[col[e0 + li] >> SHIFT], 1);
    }
    __syncthreads();
    if (tid < MAX_BINS) {
        int h = hist[tid];
        baseg[tid] = (h > 0) ? atomicAdd(&binCnt[tid], (h + 3) & ~3) : 0;  // x4 pad
        scn[tid] = h;
    }
    __syncthreads();
    for (int off = 1; off < MAX_BINS; off <<= 1) {
        int a = (tid >= off && tid < MAX_BINS) ? scn[tid - off] : 0;
        __syncthreads();
        if (tid < MAX_BINS) scn[tid] += a;
        __syncthreads();
    }
    if (tid < MAX_BINS) lofs[tid] = scn[tid] - hist[tid];
    __syncthreads();
    // pass B: re-read row+col, pack, scatter bin-contiguous into sbuf2
    for (int q = tid; q < nq; q += 512) {
        int4 r = r4[q], c = c4[q];
        int b0 = c.x >> SHIFT, b1 = c.y >> SHIFT, b2 = c.z >> SHIFT, b3 = c.w >> SHIFT;
        int p0 = lofs[b0] + atomicAdd(&cur[b0], 1);
        sbuf2[p0] = (r.x << SHIFT) | (c.x & MASK);
        int p1 = lofs[b1] + atomicAdd(&cur[b1], 1);
        sbuf2[p1] = (r.y << SHIFT) | (c.y & MASK);
        int p2 = lofs[b2] + atomicAdd(&cur[b2], 1);
        sbuf2[p2] = (r.z << SHIFT) | (c.z & MASK);
        int p3 = lofs[b3] + atomicAdd(&cur[b3], 1);
        sbuf2[p3] = (r.w << SHIFT) | (c.w & MASK);
    }
    for (int li = (nq << 2) + tid; li < cntL; li += 512) {
        int c = col[e0 + li], r = row[e0 + li], b = c >> SHIFT;
        int p = lofs[b] + atomicAdd(&cur[b], 1);
        sbuf2[p] = (r << SHIFT) | (c & MASK);
    }
    __syncthreads();
    // pass C: wave-per-bin flush, int4 chunks (baseg multiple of 4)
    int wv = tid >> 6, ln = tid & 63;
    for (int b = wv; b < MAX_BINS; b += 8) {
        int len = hist[b];
        if (len == 0) continue;
        int lo = lofs[b];
        int gb = baseg[b];
        int n4 = (len + 3) >> 2;
        for (int i4 = ln; i4 < n4; i4 += 64) {
            int base = i4 * 4;
            int4 v;
            v.x = (base + 0 < len) ? sbuf2[lo + base + 0] : SENT;
            v.y = (base + 1 < len) ? sbuf2[lo + base + 1] : SENT;
            v.z = (base + 2 < len) ? sbuf2[lo + base + 2] : SENT;
            v.w = (base + 3 < len) ? sbuf2[lo + base + 3] : SENT;
            int pos = gb + base;
            if (pos + 4 <= CAPE) *(int4*)(binned + b * CAPE + pos) = v;
        }
    }
}

// ======= stage 2 (FUSED): per-bin counting sort -> CSR + deg + dinv ==========
// + layer-1 transform. R19: binned read ONCE into 5 statically-indexed int4
// registers; histogram + placement run from registers.

__global__ void __launch_bounds__(1024) k_sort(const int* __restrict__ binned,
                                               const int* __restrict__ binCnt,
                                               int* __restrict__ csr,
                                               int* __restrict__ gptr,
                                               int* __restrict__ gcnt,
                                               float* __restrict__ dinv,
                                               const float* __restrict__ x,
                                               const float* __restrict__ W1,
                                               __half* __restrict__ z1h, int n) {
    __shared__ int cnt[NPB];
    __shared__ int scn[NPB];
    __shared__ float sW[25 * 16];
    int b = blockIdx.x;
    int t = threadIdx.x;
    if (t < NPB) cnt[t] = 0;
    if (t < 25 * 16) sW[t] = W1[t];
    __syncthreads();
    int m = min(binCnt[b], CAPE);   // multiple of 4 (padded reservations)
    int m4 = m >> 2;
    const int4* eb4 = (const int4*)(binned + b * CAPE);
    const int4 S4 = make_int4(SENT, SENT, SENT, SENT);
    int4 q0 = (t          < m4) ? eb4[t]          : S4;
    int4 q1 = (t + 1024   < m4) ? eb4[t + 1024]   : S4;
    int4 q2 = (t + 2048   < m4) ? eb4[t + 2048]   : S4;
    int4 q3 = (t + 3072   < m4) ? eb4[t + 3072]   : S4;
    int4 q4 = (t + 4096   < m4) ? eb4[t + 4096]   : S4;
#define H4(q) { \
    if (q.x != SENT) atomicAdd(&cnt[q.x & MASK], 1); \
    if (q.y != SENT) atomicAdd(&cnt[q.y & MASK], 1); \
    if (q.z != SENT) atomicAdd(&cnt[q.z & MASK], 1); \
    if (q.w != SENT) atomicAdd(&cnt[q.w & MASK], 1); }
    H4(q0) H4(q1) H4(q2) H4(q3) H4(q4)
#undef H4
    __syncthreads();
    int v = 0, pv = 0;
    if (t < NPB) {
        v = cnt[t];
        pv = (v + 3) & ~3;  // 4-aligned degree for csr segment alignment
        scn[t] = pv;
    }
    __syncthreads();
    for (int off = 1; off < NPB; off <<= 1) {
        int a = (t >= off && t < NPB) ? scn[t - off] : 0;
        __syncthreads();
        if (t < NPB) scn[t] += a;
        __syncthreads();
    }
    int node = b * NPB + t;
    float di = rsqrtf((float)(v + 1));
    if (t < NPB) {
        int excl = scn[t] - pv;  // multiple of 4
        if (node < n) {
            gptr[node] = b * CAPE + excl;
            gcnt[node] = v;
            dinv[node] = di;
        }
        cnt[t] = excl;  // reuse as cursor
    }
    __syncthreads();
#define P4(q) { \
    int e, slot; \
    e = q.x; if (e != SENT) { slot = atomicAdd(&cnt[e & MASK], 1); if (slot < CAPE) csr[b * CAPE + slot] = e >> SHIFT; } \
    e = q.y; if (e != SENT) { slot = atomicAdd(&cnt[e & MASK], 1); if (slot < CAPE) csr[b * CAPE + slot] = e >> SHIFT; } \
    e = q.z; if (e != SENT) { slot = atomicAdd(&cnt[e & MASK], 1); if (slot < CAPE) csr[b * CAPE + slot] = e >> SHIFT; } \
    e = q.w; if (e != SENT) { slot = atomicAdd(&cnt[e & MASK], 1); if (slot < CAPE) csr[b * CAPE + slot] = e >> SHIFT; } }
    P4(q0) P4(q1) P4(q2) P4(q3) P4(q4)
#undef P4
    // fused layer-1 transform for this bin's nodes
    if (t < NPB && node < n) {
        const float* xr = x + (size_t)node * 25;
        float xi[25];
#pragma unroll
        for (int k = 0; k < 25; k++) xi[k] = xr[k];
        union { int4 q[2]; __half h[16]; } u;
#pragma unroll
        for (int c = 0; c < 16; c++) {
            float a = 0.f;
#pragma unroll
            for (int k = 0; k < 25; k++) a = fmaf(xi[k], sW[k * 16 + c], a);
            u.h[c] = __float2half(a * di);
        }
        int4* o = (int4*)(z1h + (size_t)node * 16);
        o[0] = u.q[0];
        o[1] = u.q[1];
    }
}

// --- standalone xform1 (fallback path only) ----------------------------------
__global__ void __launch_bounds__(256) k_xform1(const float* __restrict__ x,
                                                const float* __restrict__ W1,
                                                const float* __restrict__ dinv,
                                                __half* __restrict__ z1h, int n) {
    __shared__ float sW[25 * 16];
    for (int t = threadIdx.x; t < 25 * 16; t += 256) sW[t] = W1[t];
    __syncthreads();
    long node = (long)blockIdx.x * 256 + threadIdx.x;
    if (node >= n) return;
    const float* xr = x + node * 25;
    float xi[25];
#pragma unroll
    for (int k = 0; k < 25; k++) xi[k] = xr[k];
    float di = dinv[node];
    union { int4 q[2]; __half h[16]; } u;
#pragma unroll
    for (int c = 0; c < 16; c++) {
        float a = 0.f;
#pragma unroll
        for (int k = 0; k < 25; k++) a = fmaf(xi[k], sW[k * 16 + c], a);
        u.h[c] = __float2half(a * di);
    }
    int4* o = (int4*)(z1h + node * 16);
    o[0] = u.q[0];
    o[1] = u.q[1];
}

// --- gather layer 1 + bias/relu + @W2: 8 lanes/node, half2 loads -------------
// R26: e-loop unrolled to 8 edges/iter (2 independent csr int4 + 8 independent
// z1h loads in flight) — the verified -4.1us MLP win. Normal (temporal) loads.
__global__ void k_gather1(const int* __restrict__ ptr, const int* __restrict__ cnt,
                          const int* __restrict__ csr, const __half* __restrict__ z1h,
                          const float* __restrict__ dinv,
                          const float* __restrict__ b1, const float* __restrict__ W2,
                          __half2* __restrict__ z2h, int n) {
    int g = threadIdx.x >> 3;
    int c2 = threadIdx.x & 7;
    int node = blockIdx.x * 32 + g;
    if (node >= n) return;
    const __half2* z1p = (const __half2*)z1h;
    int beg = ptr[node], d = cnt[node];
    __half2 sv = z1p[(size_t)node * 8 + c2];
    float a0 = __low2float(sv), a1 = __high2float(sv);
    int e = 0;
    for (; e + 8 <= d; e += 8) {
        int4 s0 = *(const int4*)(csr + beg + e);      // aligned: beg%4==0
        int4 s1 = *(const int4*)(csr + beg + e + 4);
        __half2 v0 = z1p[(size_t)s0.x * 8 + c2];
        __half2 v1 = z1p[(size_t)s0.y * 8 + c2];
        __half2 v2 = z1p[(size_t)s0.z * 8 + c2];
        __half2 v3 = z1p[(size_t)s0.w * 8 + c2];
        __half2 v4 = z1p[(size_t)s1.x * 8 + c2];
        __half2 v5 = z1p[(size_t)s1.y * 8 + c2];
        __half2 v6 = z1p[(size_t)s1.z * 8 + c2];
        __half2 v7 = z1p[(size_t)s1.w * 8 + c2];
        a0 += ((__low2float(v0) + __low2float(v1)) + (__low2float(v2) + __low2float(v3))) +
              ((__low2float(v4) + __low2float(v5)) + (__low2float(v6) + __low2float(v7)));
        a1 += ((__high2float(v0) + __high2float(v1)) + (__high2float(v2) + __high2float(v3))) +
              ((__high2float(v4) + __high2float(v5)) + (__high2float(v6) + __high2float(v7)));
    }
    for (; e + 4 <= d; e += 4) {
        int4 s = *(const int4*)(csr + beg + e);
        __half2 v0 = z1p[(size_t)s.x * 8 + c2];
        __half2 v1 = z1p[(size_t)s.y * 8 + c2];
        __half2 v2 = z1p[(size_t)s.z * 8 + c2];
        __half2 v3 = z1p[(size_t)s.w * 8 + c2];
        a0 += (__low2float(v0) + __low2float(v1)) + (__low2float(v2) + __low2float(v3));
        a1 += (__high2float(v0) + __high2float(v1)) + (__high2float(v2) + __high2float(v3));
    }
    for (; e < d; e++) {
        __half2 v = z1p[(size_t)csr[beg + e] * 8 + c2];
        a0 += __low2float(v);
        a1 += __high2float(v);
    }
    float di = dinv[node];
    int cA = c2 * 2, cB = c2 * 2 + 1;
    float hA = fmaxf(fmaf(di, a0, b1[cA]), 0.f);
    float hB = fmaxf(fmaf(di, a1, b1[cB]), 0.f);
    float p0 = hA * W2[cA * 2 + 0] + hB * W2[cB * 2 + 0];
    float p1 = hA * W2[cA * 2 + 1] + hB * W2[cB * 2 + 1];
#pragma unroll
    for (int m = 1; m < 8; m <<= 1) {
        p0 += __shfl_xor(p0, m, 8);
        p1 += __shfl_xor(p1, m, 8);
    }
    if (c2 == 0) z2h[node] = __floats2half2_rn(di * p0, di * p1);
}

// --- gather layer 2: 8 lanes/node + bias + log_softmax(2) --------------------
// R26: 2 edges/lane/iteration (independent loads) for 2x MLP.
__global__ void k_gather2(const int* __restrict__ ptr, const int* __restrict__ cnt,
                          const int* __restrict__ csr, const __half2* __restrict__ z2h,
                          const float* __restrict__ dinv,
                          const float* __restrict__ b2, float* __restrict__ out, int n) {
    int g = threadIdx.x >> 3;
    int c = threadIdx.x & 7;
    int node = blockIdx.x * 32 + g;
    if (node >= n) return;
    int beg = ptr[node], d = cnt[node];
    float a0 = 0.f, a1 = 0.f;
    int e = c;
    for (; e + 8 < d; e += 16) {
        int i0 = csr[beg + e];
        int i1 = csr[beg + e + 8];
        __half2 w0 = z2h[i0];
        __half2 w1 = z2h[i1];
        a0 += __low2float(w0) + __low2float(w1);
        a1 += __high2float(w0) + __high2float(w1);
    }
    for (; e < d; e += 8) {
        __half2 v = z2h[csr[beg + e]];
        a0 += __low2float(v);
        a1 += __high2float(v);
    }
#pragma unroll
    for (int m = 1; m < 8; m <<= 1) {
        a0 += __shfl_xor(a0, m, 8);
        a1 += __shfl_xor(a1, m, 8);
    }
    if (c == 0) {
        __half2 self = z2h[node];
        a0 += __low2float(self);
        a1 += __high2float(self);
        float di = dinv[node];
        float h0 = fmaf(di, a0, b2[0]);
        float h1 = fmaf(di, a1, b2[1]);
        float mx = fmaxf(h0, h1);
        float lse = mx + log1pf(expf(fminf(h0, h1) - mx));
        ((float2*)out)[node] = make_float2(h0 - lse, h1 - lse);
    }
}

// ===================== fallback: round-2 CSR pipeline ========================

__global__ void k_zero(int* cnt, int n) {
    int i = blockIdx.x * blockDim.x + threadIdx.x;
    if (i < n) cnt[i] = 0;
}

__global__ void k_count_pos(const int* __restrict__ col, int e,
                            int* __restrict__ cnt, int* __restrict__ pos) {
    int i = blockIdx.x * blockDim.x + threadIdx.x;
    if (i < e) pos[i] = atomicAdd(&cnt[col[i]], 1);
}

__global__ void k_scan1(const int* __restrict__ cnt, int n,
                        int* __restrict__ excl, int* __restrict__ bsum) {
    __shared__ int s[256];
    int i = blockIdx.x * 256 + threadIdx.x;
    int v = (i < n) ? cnt[i] : 0;
    s[threadIdx.x] = v;
    __syncthreads();
    for (int off = 1; off < 256; off <<= 1) {
        int t = (threadIdx.x >= off) ? s[threadIdx.x - off] : 0;
        __syncthreads();
        s[threadIdx.x] += t;
        __syncthreads();
    }
    if (i < n) excl[i] = s[threadIdx.x] - v;
    if (threadIdx.x == 255) bsum[blockIdx.x] = s[255];
}

__global__ void k_scan2(int* __restrict__ bsum, int nb) {
    __shared__ int s[1024];
    int v = (threadIdx.x < nb) ? bsum[threadIdx.x] : 0;
    s[threadIdx.x] = v;
    __syncthreads();
    for (int off = 1; off < 1024; off <<= 1) {
        int t = (threadIdx.x >= off) ? s[threadIdx.x - off] : 0;
        __syncthreads();
        s[threadIdx.x] += t;
        __syncthreads();
    }
    if (threadIdx.x < nb) bsum[threadIdx.x] = s[threadIdx.x] - v;
}

__global__ void k_scan3(int* __restrict__ excl, const int* __restrict__ boff, int n) {
    int i = blockIdx.x * 256 + threadIdx.x;
    if (i < n) excl[i] += boff[blockIdx.x];
}

__global__ void k_place(const int* __restrict__ row, const int* __restrict__ col,
                        const int* __restrict__ pos, const int* __restrict__ ptr,
                        int e, int* __restrict__ csr) {
    int i = blockIdx.x * blockDim.x + threadIdx.x;
    if (i >= e) return;
    csr[ptr[col[i]] + pos[i]] = row[i];
}

__global__ void k_dinv_from_cnt(const int* __restrict__ cnt, float* __restrict__ dinv, int n) {
    int i = blockIdx.x * blockDim.x + threadIdx.x;
    if (i < n) dinv[i] = rsqrtf((float)(cnt[i] + 1));
}

__global__ void k_gather1_fb(const int* __restrict__ ptr, const int* __restrict__ cnt,
                             const int* __restrict__ csr, const __half* __restrict__ z1h,
                             const float* __restrict__ dinv,
                             const float* __restrict__ b1, const float* __restrict__ W2,
                             __half2* __restrict__ z2h, int n) {
    int g = threadIdx.x >> 3;
    int c2 = threadIdx.x & 7;
    int node = blockIdx.x * 32 + g;
    if (node >= n) return;
    const __half2* z1p = (const __half2*)z1h;
    int beg = ptr[node], d = cnt[node];
    __half2 sv = z1p[(size_t)node * 8 + c2];
    float a0 = __low2float(sv), a1 = __high2float(sv);
    for (int e = 0; e < d; e++) {
        __half2 v = z1p[(size_t)csr[beg + e] * 8 + c2];
        a0 += __low2float(v);
        a1 += __high2float(v);
    }
    float di = dinv[node];
    int cA = c2 * 2, cB = c2 * 2 + 1;
    float hA = fmaxf(fmaf(di, a0, b1[cA]), 0.f);
    float hB = fmaxf(fmaf(di, a1, b1[cB]), 0.f);
    float p0 = hA * W2[cA * 2 + 0] + hB * W2[cB * 2 + 0];
    float p1 = hA * W2[cA * 2 + 1] + hB * W2[cB * 2 + 1];
#pragma unroll
    for (int m = 1; m < 8; m <<= 1) {
        p0 += __shfl_xor(p0, m, 8);
        p1 += __shfl_xor(p1, m, 8);
    }
    if (c2 == 0) z2h[node] = __floats2half2_rn(di * p0, di * p1);
}

// ============================== host launcher ================================

extern "C" void kernel_launch(void* const* d_in, const int* in_sizes, int n_in,
                              void* d_out, int out_size, void* d_ws, size_t ws_size,
                              hipStream_t stream) {
    const float* x  = (const float*)d_in[0];
    const int*   ei = (const int*)d_in[1];
    const float* W1 = (const float*)d_in[2];
    const float* b1 = (const float*)d_in[3];
    const float* W2 = (const float*)d_in[4];
    const float* b2 = (const float*)d_in[5];
    float* out = (float*)d_out;

    const int N = in_sizes[0] / 25;
    const int E = in_sizes[1] / 2;
    const int* row = ei;
    const int* col = ei + E;

    const int nbins = (N + NPB - 1) / NPB;
    const int gN = (N + THREADS - 1) / THREADS;
    const int gE = (E + THREADS - 1) / THREADS;

    size_t off = 0;
    auto take = [&](size_t bytes) { size_t o = off; off = (off + bytes + 255) & ~(size_t)255; return o; };
    size_t o_binCnt = take(MAX_BINS * sizeof(int));
    size_t o_binned = take((size_t)nbins * CAPE * sizeof(int));
    size_t o_csr    = take((size_t)nbins * CAPE * sizeof(int));
    size_t o_ptr    = take((size_t)N * sizeof(int));
    size_t o_cnt    = take((size_t)N * sizeof(int));
    size_t o_dinv   = take((size_t)N * sizeof(float));
    size_t o_z1h    = take((size_t)N * 16 * sizeof(__half));
    size_t o_z2h    = take((size_t)N * sizeof(__half2));
    size_t need_v17 = off;

    // bin load: mu + 8*sigma + 3*NPB pad (covers both x4 reservation pad and
    // csr alignment pad, each bounded by 3*BIN_BLOCKS=1536=3*NPB)
    double mu = (double)E / (double)nbins;
    bool cap_ok = (mu + 8.0 * sqrt(mu) + 3.0 * NPB) < (double)CAPE;
    const int per = (((E + BIN_BLOCKS - 1) / BIN_BLOCKS) + 3) & ~3;
    size_t dynLds = (size_t)per * 4 + 64;  // sbuf2 only (4B/edge)
    bool lds_ok = dynLds <= 60 * 1024;
    bool use_v17 = (nbins <= MAX_BINS) && (ws_size >= need_v17) &&
                   (N <= NPB * MAX_BINS) && cap_ok && lds_ok &&
                   (3 * BIN_BLOCKS <= 3 * NPB);

    char* wsb = (char*)d_ws;
    if (use_v17) {
        int*     binCnt = (int*)(wsb + o_binCnt);
        int*     binned = (int*)(wsb + o_binned);
        int*     csr    = (int*)(wsb + o_csr);
        int*     ptr    = (int*)(wsb + o_ptr);
        int*     cnt    = (int*)(wsb + o_cnt);
        float*   dinv   = (float*)(wsb + o_dinv);
        __half*  z1h    = (__half*)(wsb + o_z1h);
        __half2* z2h    = (__half2*)(wsb + o_z2h);

        hipMemsetAsync(binCnt, 0, MAX_BINS * sizeof(int), stream);
        k_bin<<<BIN_BLOCKS, 512, dynLds, stream>>>(row, col, E, binCnt, binned);
        k_sort<<<nbins, 1024, 0, stream>>>(binned, binCnt, csr, ptr, cnt, dinv, x, W1, z1h, N);
        k_gather1<<<(N + 31) / 32, 256, 0, stream>>>(ptr, cnt, csr, z1h, dinv, b1, W2, z2h, N);
        k_gather2<<<(N + 31) / 32, 256, 0, stream>>>(ptr, cnt, csr, z2h, dinv, b2, out, N);
    } else {
        char* w = wsb;
        int*     cnt  = (int*)w;     w += (size_t)N * sizeof(int);
        int*     ptr  = (int*)w;     w += (size_t)N * sizeof(int);
        int*     pos  = (int*)w;     w += (size_t)E * sizeof(int);
        int*     csr  = (int*)w;     w += (size_t)E * sizeof(int);
        int*     bsum = (int*)w;     w += (size_t)1024 * sizeof(int);
        float*   dinv = (float*)w;   w += (size_t)N * sizeof(float);
        __half*  z1h  = (__half*)w;  w += (size_t)N * 16 * sizeof(__half);
        __half2* z2h  = (__half2*)w; w += (size_t)N * sizeof(__half2);
        const int NB = (N + 255) / 256;

        k_zero<<<gN, THREADS, 0, stream>>>(cnt, N);
        k_count_pos<<<gE, THREADS, 0, stream>>>(col, E, cnt, pos);
        k_scan1<<<NB, 256, 0, stream>>>(cnt, N, ptr, bsum);
        k_scan2<<<1, 1024, 0, stream>>>(bsum, NB);
        k_scan3<<<NB, 256, 0, stream>>>(ptr, bsum, N);
        k_place<<<gE, THREADS, 0, stream>>>(row, col, pos, ptr, E, csr);
        k_dinv_from_cnt<<<gN, THREADS, 0, stream>>>(cnt, dinv, N);
        k_xform1<<<gN, 256, 0, stream>>>(x, W1, dinv, z1h, N);
        k_gather1_fb<<<(N + 31) / 32, 256, 0, stream>>>(ptr, cnt, csr, z1h, dinv, b1, W2, z2h, N);
        k_gather2<<<(N + 31) / 32, 256, 0, stream>>>(ptr, cnt, csr, z2h, dinv, b2, out, N);
    }
}